// Round 8
// baseline (237.479 us; speedup 1.0000x reference)
//
#include <hip/hip_runtime.h>
#include <hip/hip_bf16.h>
#include <math.h>

// DIEN bf16-MFMA v6: v5 + vmcnt-drain amortization:
//  - x global loads batched 4 steps/iter (3 of 4 barriers load-free)
//  - hs stores collected from hbuf via staging threads (coalesced uint2) and
//    flushed 4 t-planes every 4th step
//  - dot phase on waves 4-7 (L2 on 0-3) to balance barrier arrival
// ws layout (bytes): unchanged from v5.

#define LK 0.0003f

typedef __attribute__((ext_vector_type(8))) short short8;
typedef __attribute__((ext_vector_type(4))) float f32x4;

union U8 { short8 s; unsigned short u[8]; };

__device__ __forceinline__ float sigf(float x) {
    return __builtin_amdgcn_rcpf(1.0f + __expf(-x));
}
__device__ __forceinline__ float tanhfast(float x) {
    return fmaf(2.0f, __builtin_amdgcn_rcpf(1.0f + __expf(-2.0f * x)), -1.0f);
}
__device__ __forceinline__ float lky(float v) { return v >= 0.0f ? v : LK * v; }
__device__ __forceinline__ unsigned short f2bf(float f) {
    __bf16 b = (__bf16)f;
    return *reinterpret_cast<unsigned short*>(&b);
}
__device__ __forceinline__ unsigned pk2(float a, float b) {
    return (unsigned)f2bf(a) | ((unsigned)f2bf(b) << 16);
}
__device__ __forceinline__ float bf2f(unsigned short h) {
    return __uint_as_float(((unsigned)h) << 16);
}
// XOR swizzle: 16B-slot permute within 8-row stripes -> <=2-way bank aliasing (free)
__device__ __forceinline__ int swz(int row, int kbyte, int stride) {
    return row * stride + (kbyte ^ ((row & 7) << 4));
}
__device__ __forceinline__ f32x4 mfma16(short8 a, short8 b, f32x4 c) {
    return __builtin_amdgcn_mfma_f32_16x16x32_bf16(a, b, c, 0, 0, 0);
}

// ---------------- pack & transpose all weights to bf16 [n][k] panels ----------------
__global__ void pack_all(
    const float* __restrict__ gW, const float* __restrict__ gU,
    const float* __restrict__ aWu, const float* __restrict__ aWr, const float* __restrict__ aWc,
    const float* __restrict__ aUu, const float* __restrict__ aUr, const float* __restrict__ aUc,
    const float* __restrict__ tW1, const float* __restrict__ tW2,
    const float* __restrict__ dW1, const float* __restrict__ dW2,
    const float* __restrict__ abu, const float* __restrict__ abr, const float* __restrict__ abc,
    unsigned short* __restrict__ Wg, unsigned short* __restrict__ Ug,
    unsigned short* __restrict__ Wau, unsigned short* __restrict__ Uau,
    unsigned short* __restrict__ WA, unsigned short* __restrict__ WN,
    unsigned short* __restrict__ AW2,
    unsigned short* __restrict__ DW1, unsigned short* __restrict__ DW2,
    float* __restrict__ bp)
{
    int i = blockIdx.x * 256 + threadIdx.x;
    if (i < 49152) {                                  // Wg/Ug: [n<384][k<128]
        int n = i >> 7, k = i & 127;
        Wg[i] = f2bf(gW[k * 384 + n]);
        Ug[i] = f2bf(gU[k * 384 + n]);
    } else if (i < 98304) {                           // Wau/Uau
        int j = i - 49152; int n = j >> 7, k = j & 127;
        int g = n >> 7, c = n & 127;
        const float* s = (g == 0) ? aWu : (g == 1) ? aWr : aWc;
        const float* u = (g == 0) ? aUu : (g == 1) ? aUr : aUc;
        Wau[j] = f2bf(s[k * 128 + c]);
        Uau[j] = f2bf(u[k * 128 + c]);
    } else if (i < 131072) {                          // WA: [n<128][k<256]
        int j = i - 98304; int n = j >> 8, k = j & 255;
        float v = (k < 128) ? (tW1[k * 128 + n] - tW1[(128 + k) * 128 + n])
                            : tW1[(384 + (k - 128)) * 128 + n];
        WA[j] = f2bf(v);
    } else if (i < 147456) {                          // WN: [n<128][k<128]
        int j = i - 131072; int n = j >> 7, k = j & 127;
        WN[j] = f2bf(tW1[(128 + k) * 128 + n] + tW1[(256 + k) * 128 + n]);
    } else if (i < 155648) {                          // AW2: [n<64][k<128]
        int j = i - 147456; int n = j >> 7, k = j & 127;
        AW2[j] = f2bf(tW2[k * 64 + n]);
    } else if (i < 221184) {                          // DW1: [n<256][k<256]
        int j = i - 155648; int n = j >> 8, k = j & 255;
        DW1[j] = f2bf(dW1[k * 256 + n]);
    } else if (i < 253952) {                          // DW2: [n<128][k<256]
        int j = i - 221184; int n = j >> 8, k = j & 255;
        DW2[j] = f2bf(dW2[k * 128 + n]);
    } else if (i < 254336) {
        int j = i - 253952;
        bp[j] = (j < 128) ? abu[j] : (j < 256) ? abr[j - 128] : abc[j - 256];
    }
}

// ---------------- nterm = news @ WN + b1  (4096 x 128, K=128) ----------------
__global__ __launch_bounds__(512, 2) void nterm_kernel(
    const float* __restrict__ inputs, const unsigned short* __restrict__ WN,
    const float* __restrict__ b1, float* __restrict__ nterm)
{
    __shared__ __align__(16) unsigned char nb[64 * 256];  // [64][128] bf16 swz

    const int tid = threadIdx.x;
    const int wv = tid >> 6, l = tid & 63, l15 = l & 15, lg = l >> 4;
    const size_t b0 = (size_t)blockIdx.x * 64;

    {
        int r = tid >> 3, c = tid & 7;
        const float* src = inputs + ((b0 + r) * 51 + 50) * 128 + c * 16;
        float4 v0 = *(const float4*)(src);
        float4 v1 = *(const float4*)(src + 4);
        float4 v2 = *(const float4*)(src + 8);
        float4 v3 = *(const float4*)(src + 12);
        *(uint4*)(nb + swz(r, c * 32, 256)) =
            make_uint4(pk2(v0.x, v0.y), pk2(v0.z, v0.w), pk2(v1.x, v1.y), pk2(v1.z, v1.w));
        *(uint4*)(nb + swz(r, c * 32 + 16, 256)) =
            make_uint4(pk2(v2.x, v2.y), pk2(v2.z, v2.w), pk2(v3.x, v3.y), pk2(v3.z, v3.w));
    }
    __syncthreads();

    short8 wf[4];
#pragma unroll
    for (int kt = 0; kt < 4; ++kt)
        wf[kt] = *(const short8*)(WN + (wv * 16 + l15) * 128 + kt * 32 + lg * 8);

    f32x4 acc[4];
#pragma unroll
    for (int rt = 0; rt < 4; ++rt) acc[rt] = (f32x4){0.f, 0.f, 0.f, 0.f};
#pragma unroll
    for (int rt = 0; rt < 4; ++rt)
#pragma unroll
        for (int kt = 0; kt < 4; ++kt) {
            short8 axx = *(const short8*)(nb + swz(rt * 16 + l15, kt * 64 + lg * 16, 256));
            acc[rt] = mfma16(axx, wf[kt], acc[rt]);
        }
    float bb = b1[wv * 16 + l15];
#pragma unroll
    for (int rt = 0; rt < 4; ++rt)
#pragma unroll
        for (int j = 0; j < 4; ++j)
            nterm[(b0 + rt * 16 + lg * 4 + j) * 128 + wv * 16 + l15] = acc[rt][j] + bb;
}

// ---------------- GRU + attention fused persistent recurrence ----------------
// 512 threads = 8 waves, 16 batch rows/block, grid 256. One barrier per step.
// Pipeline: step t computes h_t; L1(t-1); L2(t-2); dot->ats(t-3). 3 drain iters.
__global__ __launch_bounds__(512, 2) void gru_attn(
    const float* __restrict__ inputs, const unsigned short* __restrict__ Wt,
    const unsigned short* __restrict__ Ut, const float* __restrict__ gb,
    const unsigned short* __restrict__ WA, const unsigned short* __restrict__ AW2,
    const float* __restrict__ ab2, const float* __restrict__ nterm,
    const float* __restrict__ W3, const float* __restrict__ b3,
    unsigned short* __restrict__ hs, float* __restrict__ ats)
{
    __shared__ __align__(16) unsigned char xbuf[2][4096];   // x_t bf16 [16][128] swz
    __shared__ __align__(16) unsigned char hbuf[2][4096];   // h   bf16 [16][128] swz
    __shared__ __align__(16) unsigned char pbuf[2][4096];   // h*news bf16 swz
    __shared__ __align__(16) unsigned char a1buf[2][4096];  // a1 bf16 [16][128] swz
    __shared__ float a2buf[2][16 * 64];
    __shared__ float w3l[64];

    const int tid = threadIdx.x;
    const int wv = tid >> 6, l = tid & 63, l15 = l & 15, lg = l >> 4;
    const size_t row0 = (size_t)blockIdx.x * 16;
    const int ucol = wv * 16 + l15;            // GRU out col AND attn L1 col

    // --- persistent weight fragments ---
    short8 wf[3][4], uf[3][4];
#pragma unroll
    for (int g = 0; g < 3; ++g)
#pragma unroll
        for (int kt = 0; kt < 4; ++kt) {
            int n = g * 128 + ucol;
            int k0 = kt * 32 + lg * 8;
            wf[g][kt] = *(const short8*)(Wt + n * 128 + k0);
            uf[g][kt] = *(const short8*)(Ut + n * 128 + k0);
        }
    short8 waf[8];
#pragma unroll
    for (int kt = 0; kt < 8; ++kt)
        waf[kt] = *(const short8*)(WA + ucol * 256 + kt * 32 + lg * 8);
    short8 w2f[4];
    const int n2 = (wv & 3) * 16 + l15;
    if (wv < 4) {
#pragma unroll
        for (int kt = 0; kt < 4; ++kt)
            w2f[kt] = *(const short8*)(AW2 + n2 * 128 + kt * 32 + lg * 8);
    }
    const float b2v = (wv < 4) ? ab2[n2] : 0.f;
    const float b3v = b3[0];
    if (tid < 64) w3l[tid] = W3[tid];

    const float bx2 = gb[256 + ucol], bh2 = gb[640 + ucol];
    const float bz  = gb[ucol] + gb[384 + ucol];
    const float br  = gb[128 + ucol] + gb[512 + ucol];

    float nt4[4], news4[4];
#pragma unroll
    for (int j = 0; j < 4; ++j) {
        int m = lg * 4 + j;
        nt4[j]   = nterm[(row0 + m) * 128 + ucol];
        news4[j] = inputs[((row0 + m) * 51 + 50) * 128 + ucol];
    }

    const int sr = tid >> 5, ss = tid & 31;    // staging: row, 4-elem chunk
    const float* xsrc = inputs + (row0 + sr) * 51 * 128 + ss * 4;
    unsigned short* hdst = hs + (row0 + sr) * 50 * 128 + ss * 4;

    *(uint2*)(hbuf[0] + tid * 8) = make_uint2(0u, 0u);
    {
        float4 v = *(const float4*)(xsrc);
        *(uint2*)(xbuf[0] + swz(sr, ss * 8, 256)) = make_uint2(pk2(v.x, v.y), pk2(v.z, v.w));
    }
    float hreg[4] = {0.f, 0.f, 0.f, 0.f};
    float4 xr4[4];
    uint2 hsb[4];
    __syncthreads();

    for (int t = 0; t <= 52; ++t) {
        const int p = t & 1;

        // --- batched x prefetch: 4 steps' loads every 4th iter ---
        if ((t & 3) == 0 && t < 49) {
#pragma unroll
            for (int k = 0; k < 4; ++k)
                if (t + 1 + k < 50)
                    xr4[k] = *(const float4*)(xsrc + (size_t)(t + 1 + k) * 128);
        }

        // --- collect h_{t-1} from hbuf (coalesced), flush 4 planes every 4th iter ---
        if (t >= 1 && t <= 50) {
            hsb[(t - 1) & 3] = *(const uint2*)(hbuf[p] + swz(sr, ss * 8, 256));
            if (t >= 4 && (t & 3) == 0) {
#pragma unroll
                for (int k = 0; k < 4; ++k)
                    *(uint2*)(hdst + (size_t)(t - 4 + k) * 128) = hsb[k];
            } else if (t == 50) {
                *(uint2*)(hdst + (size_t)48 * 128) = hsb[0];
                *(uint2*)(hdst + (size_t)49 * 128) = hsb[1];
            }
        }

        short8 ah[4];
        if (t <= 50) {
#pragma unroll
            for (int kt = 0; kt < 4; ++kt)
                ah[kt] = *(const short8*)(hbuf[p] + swz(l15, kt * 64 + lg * 16, 256));
        }

        // --- GRU step t ---
        if (t < 50) {
            short8 ax[4];
#pragma unroll
            for (int kt = 0; kt < 4; ++kt)
                ax[kt] = *(const short8*)(xbuf[p] + swz(l15, kt * 64 + lg * 16, 256));
            f32x4 accx[3], acch[3];
#pragma unroll
            for (int g = 0; g < 3; ++g) {
                accx[g] = (f32x4){0.f, 0.f, 0.f, 0.f};
                acch[g] = (f32x4){0.f, 0.f, 0.f, 0.f};
            }
#pragma unroll
            for (int kt = 0; kt < 4; ++kt)
#pragma unroll
                for (int g = 0; g < 3; ++g) {
                    accx[g] = mfma16(ax[kt], wf[g][kt], accx[g]);
                    acch[g] = mfma16(ah[kt], uf[g][kt], acch[g]);
                }
#pragma unroll
            for (int j = 0; j < 4; ++j) {
                int m = lg * 4 + j;
                float z  = sigf(accx[0][j] + acch[0][j] + bz);
                float r  = sigf(accx[1][j] + acch[1][j] + br);
                float hc = tanhfast(accx[2][j] + bx2 + r * (acch[2][j] + bh2));
                float hn = fmaf(z, hreg[j] - hc, hc);
                hreg[j] = hn;
                *(unsigned short*)(hbuf[p ^ 1] + swz(m, ucol * 2, 256)) = f2bf(hn);
                *(unsigned short*)(pbuf[p ^ 1] + swz(m, ucol * 2, 256)) = f2bf(hn * news4[j]);
            }
        }

        // --- attn L1 for step t-1 : a1 = relu(h@Wa + p@Wd + nterm) ---
        if (t >= 1 && t <= 50) {
            short8 pa[4];
#pragma unroll
            for (int kt = 0; kt < 4; ++kt)
                pa[kt] = *(const short8*)(pbuf[p] + swz(l15, kt * 64 + lg * 16, 256));
            f32x4 lacc = (f32x4){0.f, 0.f, 0.f, 0.f};
#pragma unroll
            for (int kt = 0; kt < 4; ++kt) lacc = mfma16(ah[kt], waf[kt], lacc);
#pragma unroll
            for (int kt = 0; kt < 4; ++kt) lacc = mfma16(pa[kt], waf[4 + kt], lacc);
#pragma unroll
            for (int j = 0; j < 4; ++j) {
                float v = fmaxf(lacc[j] + nt4[j], 0.f);
                *(unsigned short*)(a1buf[p] + swz(lg * 4 + j, ucol * 2, 256)) = f2bf(v);
            }
        }

        // --- attn L2 for step t-2 : a2 = relu(a1@W2 + b2)  (waves 0-3) ---
        if (t >= 2 && t <= 51 && wv < 4) {
            f32x4 c2 = (f32x4){0.f, 0.f, 0.f, 0.f};
#pragma unroll
            for (int kt = 0; kt < 4; ++kt) {
                short8 aa = *(const short8*)(a1buf[p ^ 1] + swz(l15, kt * 64 + lg * 16, 256));
                c2 = mfma16(aa, w2f[kt], c2);
            }
#pragma unroll
            for (int j = 0; j < 4; ++j)
                a2buf[p][(lg * 4 + j) * 64 + n2] = fmaxf(c2[j] + b2v, 0.f);
        }

        // --- dot for step t-3 : ats = sig(a2.w3 + b3)  (waves 4-7) ---
        if (t >= 3 && tid >= 256) {
            int rrow = (tid - 256) >> 5, cc = tid & 31;
            const float* a2r = &a2buf[p ^ 1][rrow * 64];
            float s = a2r[cc] * w3l[cc] + a2r[cc + 32] * w3l[cc + 32];
            s += __shfl_xor(s, 16, 32);
            s += __shfl_xor(s, 8, 32);
            s += __shfl_xor(s, 4, 32);
            s += __shfl_xor(s, 2, 32);
            s += __shfl_xor(s, 1, 32);
            if ((tid & 31) == 0) ats[(row0 + rrow) * 50 + (t - 3)] = sigf(s + b3v);
        }

        if (t < 49) {
            float4 xv = xr4[t & 3];
            *(uint2*)(xbuf[p ^ 1] + swz(sr, ss * 8, 256)) =
                make_uint2(pk2(xv.x, xv.y), pk2(xv.z, xv.w));
        }
        __syncthreads();
    }
}

// ---------------- AUGRU: MFMA recurrence, single barrier per step ----------------
__global__ __launch_bounds__(512, 2) void augru_mfma(
    const unsigned short* __restrict__ hsrc, const unsigned short* __restrict__ Wt,
    const unsigned short* __restrict__ Ut, const float* __restrict__ bp,
    const float* __restrict__ ats, float* __restrict__ hf)
{
    __shared__ __align__(16) unsigned char xbuf[2][4096];
    __shared__ __align__(16) unsigned char hbuf[2][4096];
    __shared__ float atsl[16 * 50];

    const int tid = threadIdx.x;
    const int wv = tid >> 6, l = tid & 63, l15 = l & 15, lg = l >> 4;
    const size_t row0 = (size_t)blockIdx.x * 16;
    const int ucol = wv * 16 + l15;

    short8 wf[3][4], uf[3][4];
#pragma unroll
    for (int g = 0; g < 3; ++g)
#pragma unroll
        for (int kt = 0; kt < 4; ++kt) {
            int n = g * 128 + ucol;
            int k0 = kt * 32 + lg * 8;
            wf[g][kt] = *(const short8*)(Wt + n * 128 + k0);
            uf[g][kt] = *(const short8*)(Ut + n * 128 + k0);
        }
    const float bx0 = bp[ucol], bx1 = bp[128 + ucol], bx2 = bp[256 + ucol];

    const int sr = tid >> 5, ss = tid & 31;
    const unsigned short* xsrc = hsrc + (row0 + sr) * 50 * 128 + ss * 4;

    *(uint2*)(hbuf[0] + tid * 8) = make_uint2(0u, 0u);
    if (tid < 400) {
        atsl[tid] = ats[row0 * 50 + tid];
        atsl[tid + 400] = ats[row0 * 50 + tid + 400];
    }
    {
        uint2 v = *(const uint2*)(xsrc);
        *(uint2*)(xbuf[0] + swz(sr, ss * 8, 256)) = v;
    }
    float hreg[4] = {0.f, 0.f, 0.f, 0.f};
    uint2 xb[4];
    __syncthreads();

    for (int t = 0; t < 50; ++t) {
        const int p = t & 1;
        if ((t & 3) == 0 && t < 49) {
#pragma unroll
            for (int k = 0; k < 4; ++k)
                if (t + 1 + k < 50)
                    xb[k] = *(const uint2*)(xsrc + (size_t)(t + 1 + k) * 128);
        }

        short8 ax[4], ah[4];
#pragma unroll
        for (int kt = 0; kt < 4; ++kt) {
            int off = swz(l15, kt * 64 + lg * 16, 256);
            ax[kt] = *(const short8*)(xbuf[p] + off);
            ah[kt] = *(const short8*)(hbuf[p] + off);
        }
        f32x4 accx[3], acch[3];
#pragma unroll
        for (int g = 0; g < 3; ++g) {
            accx[g] = (f32x4){0.f, 0.f, 0.f, 0.f};
            acch[g] = (f32x4){0.f, 0.f, 0.f, 0.f};
        }
#pragma unroll
        for (int kt = 0; kt < 4; ++kt)
#pragma unroll
            for (int g = 0; g < 3; ++g) {
                accx[g] = mfma16(ax[kt], wf[g][kt], accx[g]);
                acch[g] = mfma16(ah[kt], uf[g][kt], acch[g]);
            }
#pragma unroll
        for (int j = 0; j < 4; ++j) {
            int m = lg * 4 + j;
            float u  = sigf(accx[0][j] + bx0 + acch[0][j]);
            float r  = sigf(accx[1][j] + bx1 + acch[1][j]);
            float c  = tanhfast(accx[2][j] + bx2 + r * acch[2][j]);
            float uu = atsl[m * 50 + t] * u;
            float hn = fmaf(uu, c - hreg[j], hreg[j]);
            hreg[j] = hn;
            *(unsigned short*)(hbuf[p ^ 1] + swz(m, ucol * 2, 256)) = f2bf(hn);
        }
        if (t < 49) *(uint2*)(xbuf[p ^ 1] + swz(sr, ss * 8, 256)) = xb[t & 3];
        __syncthreads();
    }
#pragma unroll
    for (int j = 0; j < 4; ++j)
        hf[(row0 + lg * 4 + j) * 128 + ucol] = hreg[j];
}

// ---------------- final: BN + 256->256->128->1, MFMA ----------------
__global__ __launch_bounds__(256, 2) void final_mfma(
    const float* __restrict__ hfv, const float* __restrict__ inputs,
    const float* __restrict__ gam, const float* __restrict__ bet,
    const float* __restrict__ mu, const float* __restrict__ var,
    const unsigned short* __restrict__ W1t, const float* __restrict__ b1,
    const unsigned short* __restrict__ W2t, const float* __restrict__ b2,
    const float* __restrict__ fW, const float* __restrict__ fb,
    float* __restrict__ out)
{
    __shared__ __align__(16) unsigned char xnb[16 * 512];  // [16][256] bf16 swz
    __shared__ __align__(16) unsigned char d1b[16 * 512];  // [16][256] bf16 swz
    __shared__ float d2b[16 * 132];
    __shared__ float wfl[128];

    const int tid = threadIdx.x;
    const int wv = tid >> 6, l = tid & 63, l15 = l & 15, lg = l >> 4;
    const size_t r0 = (size_t)blockIdx.x * 16;

    short8 w1f[4][8];
#pragma unroll
    for (int p = 0; p < 4; ++p)
#pragma unroll
        for (int kt = 0; kt < 8; ++kt) {
            int n = wv * 64 + p * 16 + l15;
            w1f[p][kt] = *(const short8*)(W1t + n * 256 + kt * 32 + lg * 8);
        }
    short8 w2f[2][8];
#pragma unroll
    for (int p = 0; p < 2; ++p)
#pragma unroll
        for (int kt = 0; kt < 8; ++kt) {
            int n = wv * 32 + p * 16 + l15;
            w2f[p][kt] = *(const short8*)(W2t + n * 256 + kt * 32 + lg * 8);
        }
    if (tid < 128) wfl[tid] = fW[tid];

    {   // stage BN-normalized input, bf16 swz
        int r = tid >> 4, c = tid & 15, k0 = c * 16;
        float v[16];
#pragma unroll
        for (int q = 0; q < 16; ++q) {
            int k = k0 + q;
            float x = (k < 128) ? hfv[(r0 + r) * 128 + k]
                                : inputs[((r0 + r) * 51 + 50) * 128 + (k - 128)];
            float s = gam[k] * rsqrtf(var[k] + 0.001f);
            v[q] = (x - mu[k]) * s + bet[k];
        }
        *(uint4*)(xnb + swz(r, k0 * 2, 512)) =
            make_uint4(pk2(v[0], v[1]), pk2(v[2], v[3]), pk2(v[4], v[5]), pk2(v[6], v[7]));
        *(uint4*)(xnb + swz(r, k0 * 2 + 16, 512)) =
            make_uint4(pk2(v[8], v[9]), pk2(v[10], v[11]), pk2(v[12], v[13]), pk2(v[14], v[15]));
    }
    __syncthreads();

    // L1: [16][256] @ [256][256], leaky
    f32x4 a1[4];
#pragma unroll
    for (int p = 0; p < 4; ++p) a1[p] = (f32x4){0.f, 0.f, 0.f, 0.f};
#pragma unroll
    for (int kt = 0; kt < 8; ++kt) {
        short8 axx = *(const short8*)(xnb + swz(l15, kt * 64 + lg * 16, 512));
#pragma unroll
        for (int p = 0; p < 4; ++p) a1[p] = mfma16(axx, w1f[p][kt], a1[p]);
    }
#pragma unroll
    for (int p = 0; p < 4; ++p) {
        float bb = b1[wv * 64 + p * 16 + l15];
#pragma unroll
        for (int j = 0; j < 4; ++j) {
            int row = lg * 4 + j, col = wv * 64 + p * 16 + l15;
            *(unsigned short*)(d1b + swz(row, col * 2, 512)) = f2bf(lky(a1[p][j] + bb));
        }
    }
    __syncthreads();

    // L2: [16][256] @ [256][128], leaky
    f32x4 a2[2];
#pragma unroll
    for (int p = 0; p < 2; ++p) a2[p] = (f32x4){0.f, 0.f, 0.f, 0.f};
#pragma unroll
    for (int kt = 0; kt < 8; ++kt) {
        short8 axx = *(const short8*)(d1b + swz(l15, kt * 64 + lg * 16, 512));
#pragma unroll
        for (int p = 0; p < 2; ++p) a2[p] = mfma16(axx, w2f[p][kt], a2[p]);
    }
#pragma unroll
    for (int p = 0; p < 2; ++p) {
        float bb = b2[wv * 32 + p * 16 + l15];
#pragma unroll
        for (int j = 0; j < 4; ++j)
            d2b[(lg * 4 + j) * 132 + wv * 32 + p * 16 + l15] = lky(a2[p][j] + bb);
    }
    __syncthreads();

    if (tid < 16) {
        float s = fb[0];
#pragma unroll 8
        for (int k = 0; k < 128; ++k) s += d2b[tid * 132 + k] * wfl[k];
        out[r0 + tid] = sigf(s);
    }
}

extern "C" void kernel_launch(void* const* d_in, const int* in_sizes, int n_in,
                              void* d_out, int out_size, void* d_ws, size_t ws_size,
                              hipStream_t stream)
{
    const float* inputs   = (const float*)d_in[0];
    const float* gru_W    = (const float*)d_in[1];
    const float* gru_U    = (const float*)d_in[2];
    const float* gru_b    = (const float*)d_in[3];
    const float* att_W1   = (const float*)d_in[4];
    const float* att_b1   = (const float*)d_in[5];
    const float* att_W2   = (const float*)d_in[6];
    const float* att_b2   = (const float*)d_in[7];
    const float* att_W3   = (const float*)d_in[8];
    const float* att_b3   = (const float*)d_in[9];
    const float* au_Wu    = (const float*)d_in[10];
    const float* au_bu    = (const float*)d_in[11];
    const float* au_Uu    = (const float*)d_in[12];
    const float* au_Wr    = (const float*)d_in[13];
    const float* au_br    = (const float*)d_in[14];
    const float* au_Ur    = (const float*)d_in[15];
    const float* au_Wc    = (const float*)d_in[16];
    const float* au_bc    = (const float*)d_in[17];
    const float* au_Uc    = (const float*)d_in[18];
    const float* bn_gamma = (const float*)d_in[19];
    const float* bn_beta  = (const float*)d_in[20];
    const float* bn_mean  = (const float*)d_in[21];
    const float* bn_var   = (const float*)d_in[22];
    const float* d_W1     = (const float*)d_in[23];
    const float* d_b1     = (const float*)d_in[24];
    const float* d_W2     = (const float*)d_in[25];
    const float* d_b2     = (const float*)d_in[26];
    const float* f_W      = (const float*)d_in[27];
    const float* f_b      = (const float*)d_in[28];

    char* w = (char*)d_ws;
    unsigned short* hs  = (unsigned short*)w;
    float* ats          = (float*)(w + 52428800);
    float* hf           = (float*)(w + 53248000);
    float* nterm        = (float*)(w + 55345152);
    unsigned short* Wg  = (unsigned short*)(w + 57442304);
    unsigned short* Ug  = (unsigned short*)(w + 57540608);
    unsigned short* Wau = (unsigned short*)(w + 57638912);
    unsigned short* Uau = (unsigned short*)(w + 57737216);
    unsigned short* WA  = (unsigned short*)(w + 57835520);
    unsigned short* WN  = (unsigned short*)(w + 57901056);
    unsigned short* AW2 = (unsigned short*)(w + 57933824);
    unsigned short* DW1 = (unsigned short*)(w + 57950208);
    unsigned short* DW2 = (unsigned short*)(w + 58081280);
    float* bp           = (float*)(w + 58146816);

    pack_all<<<994, 256, 0, stream>>>(
        gru_W, gru_U, au_Wu, au_Wr, au_Wc, au_Uu, au_Ur, au_Uc,
        att_W1, att_W2, d_W1, d_W2, au_bu, au_br, au_bc,
        Wg, Ug, Wau, Uau, WA, WN, AW2, DW1, DW2, bp);
    nterm_kernel<<<64, 512, 0, stream>>>(inputs, WN, att_b1, nterm);
    gru_attn<<<256, 512, 0, stream>>>(inputs, Wg, Ug, gru_b, WA, AW2, att_b2,
                                      nterm, att_W3, att_b3, hs, ats);
    augru_mfma<<<256, 512, 0, stream>>>(hs, Wau, Uau, bp, ats, hf);
    final_mfma<<<256, 256, 0, stream>>>(hf, inputs, bn_gamma, bn_beta, bn_mean, bn_var,
                                        DW1, d_b1, DW2, d_b2, f_W, f_b, (float*)d_out);
}

// Round 9
// 165.325 us; speedup vs baseline: 1.4364x; 1.4364x over previous
//
#include <hip/hip_runtime.h>
#include <hip/hip_bf16.h>
#include <math.h>

// DIEN bf16-MFMA v7: r7 structure + branch-free steady-state loop, MFMA-cluster
// reorder (all 32 MFMAs before gate VALU), hoisted LDS offsets, s_setprio.
// ws layout (bytes): unchanged.

#define LK 0.0003f

typedef __attribute__((ext_vector_type(8))) short short8;
typedef __attribute__((ext_vector_type(4))) float f32x4;

union U8 { short8 s; unsigned short u[8]; };

__device__ __forceinline__ float sigf(float x) {
    return __builtin_amdgcn_rcpf(1.0f + __expf(-x));
}
__device__ __forceinline__ float tanhfast(float x) {
    return fmaf(2.0f, __builtin_amdgcn_rcpf(1.0f + __expf(-2.0f * x)), -1.0f);
}
__device__ __forceinline__ float lky(float v) { return v >= 0.0f ? v : LK * v; }
__device__ __forceinline__ unsigned short f2bf(float f) {
    __bf16 b = (__bf16)f;
    return *reinterpret_cast<unsigned short*>(&b);
}
__device__ __forceinline__ unsigned pk2(float a, float b) {
    return (unsigned)f2bf(a) | ((unsigned)f2bf(b) << 16);
}
__device__ __forceinline__ float bf2f(unsigned short h) {
    return __uint_as_float(((unsigned)h) << 16);
}
__device__ __forceinline__ int swz(int row, int kbyte, int stride) {
    return row * stride + (kbyte ^ ((row & 7) << 4));
}
__device__ __forceinline__ f32x4 mfma16(short8 a, short8 b, f32x4 c) {
    return __builtin_amdgcn_mfma_f32_16x16x32_bf16(a, b, c, 0, 0, 0);
}

// ---------------- pack & transpose all weights to bf16 [n][k] panels ----------------
__global__ void pack_all(
    const float* __restrict__ gW, const float* __restrict__ gU,
    const float* __restrict__ aWu, const float* __restrict__ aWr, const float* __restrict__ aWc,
    const float* __restrict__ aUu, const float* __restrict__ aUr, const float* __restrict__ aUc,
    const float* __restrict__ tW1, const float* __restrict__ tW2,
    const float* __restrict__ dW1, const float* __restrict__ dW2,
    const float* __restrict__ abu, const float* __restrict__ abr, const float* __restrict__ abc,
    unsigned short* __restrict__ Wg, unsigned short* __restrict__ Ug,
    unsigned short* __restrict__ Wau, unsigned short* __restrict__ Uau,
    unsigned short* __restrict__ WA, unsigned short* __restrict__ WN,
    unsigned short* __restrict__ AW2,
    unsigned short* __restrict__ DW1, unsigned short* __restrict__ DW2,
    float* __restrict__ bp)
{
    int i = blockIdx.x * 256 + threadIdx.x;
    if (i < 49152) {
        int n = i >> 7, k = i & 127;
        Wg[i] = f2bf(gW[k * 384 + n]);
        Ug[i] = f2bf(gU[k * 384 + n]);
    } else if (i < 98304) {
        int j = i - 49152; int n = j >> 7, k = j & 127;
        int g = n >> 7, c = n & 127;
        const float* s = (g == 0) ? aWu : (g == 1) ? aWr : aWc;
        const float* u = (g == 0) ? aUu : (g == 1) ? aUr : aUc;
        Wau[j] = f2bf(s[k * 128 + c]);
        Uau[j] = f2bf(u[k * 128 + c]);
    } else if (i < 131072) {
        int j = i - 98304; int n = j >> 8, k = j & 255;
        float v = (k < 128) ? (tW1[k * 128 + n] - tW1[(128 + k) * 128 + n])
                            : tW1[(384 + (k - 128)) * 128 + n];
        WA[j] = f2bf(v);
    } else if (i < 147456) {
        int j = i - 131072; int n = j >> 7, k = j & 127;
        WN[j] = f2bf(tW1[(128 + k) * 128 + n] + tW1[(256 + k) * 128 + n]);
    } else if (i < 155648) {
        int j = i - 147456; int n = j >> 7, k = j & 127;
        AW2[j] = f2bf(tW2[k * 64 + n]);
    } else if (i < 221184) {
        int j = i - 155648; int n = j >> 8, k = j & 255;
        DW1[j] = f2bf(dW1[k * 256 + n]);
    } else if (i < 253952) {
        int j = i - 221184; int n = j >> 8, k = j & 255;
        DW2[j] = f2bf(dW2[k * 128 + n]);
    } else if (i < 254336) {
        int j = i - 253952;
        bp[j] = (j < 128) ? abu[j] : (j < 256) ? abr[j - 128] : abc[j - 256];
    }
}

// ---------------- nterm = news @ WN + b1 ----------------
__global__ __launch_bounds__(512, 2) void nterm_kernel(
    const float* __restrict__ inputs, const unsigned short* __restrict__ WN,
    const float* __restrict__ b1, float* __restrict__ nterm)
{
    __shared__ __align__(16) unsigned char nb[64 * 256];

    const int tid = threadIdx.x;
    const int wv = tid >> 6, l = tid & 63, l15 = l & 15, lg = l >> 4;
    const size_t b0 = (size_t)blockIdx.x * 64;

    {
        int r = tid >> 3, c = tid & 7;
        const float* src = inputs + ((b0 + r) * 51 + 50) * 128 + c * 16;
        float4 v0 = *(const float4*)(src);
        float4 v1 = *(const float4*)(src + 4);
        float4 v2 = *(const float4*)(src + 8);
        float4 v3 = *(const float4*)(src + 12);
        *(uint4*)(nb + swz(r, c * 32, 256)) =
            make_uint4(pk2(v0.x, v0.y), pk2(v0.z, v0.w), pk2(v1.x, v1.y), pk2(v1.z, v1.w));
        *(uint4*)(nb + swz(r, c * 32 + 16, 256)) =
            make_uint4(pk2(v2.x, v2.y), pk2(v2.z, v2.w), pk2(v3.x, v3.y), pk2(v3.z, v3.w));
    }
    __syncthreads();

    short8 wf[4];
#pragma unroll
    for (int kt = 0; kt < 4; ++kt)
        wf[kt] = *(const short8*)(WN + (wv * 16 + l15) * 128 + kt * 32 + lg * 8);

    f32x4 acc[4];
#pragma unroll
    for (int rt = 0; rt < 4; ++rt) acc[rt] = (f32x4){0.f, 0.f, 0.f, 0.f};
#pragma unroll
    for (int rt = 0; rt < 4; ++rt)
#pragma unroll
        for (int kt = 0; kt < 4; ++kt) {
            short8 axx = *(const short8*)(nb + swz(rt * 16 + l15, kt * 64 + lg * 16, 256));
            acc[rt] = mfma16(axx, wf[kt], acc[rt]);
        }
    float bb = b1[wv * 16 + l15];
#pragma unroll
    for (int rt = 0; rt < 4; ++rt)
#pragma unroll
        for (int j = 0; j < 4; ++j)
            nterm[(b0 + rt * 16 + lg * 4 + j) * 128 + wv * 16 + l15] = acc[rt][j] + bb;
}

// ---------------- GRU + attention fused persistent recurrence ----------------
// 512 threads = 8 waves, 16 rows/block, grid 256. One barrier per step.
// Steady-state body is branch-free; all 32 MFMAs issued before gate VALU.
__global__ __launch_bounds__(512, 2) void gru_attn(
    const float* __restrict__ inputs, const unsigned short* __restrict__ Wt,
    const unsigned short* __restrict__ Ut, const float* __restrict__ gb,
    const unsigned short* __restrict__ WA, const unsigned short* __restrict__ AW2,
    const float* __restrict__ ab2, const float* __restrict__ nterm,
    const float* __restrict__ W3, const float* __restrict__ b3,
    unsigned short* __restrict__ hs, float* __restrict__ ats)
{
    __shared__ __align__(16) unsigned char xbuf[2][4096];
    __shared__ __align__(16) unsigned char hbuf[2][4096];
    __shared__ __align__(16) unsigned char pbuf[2][4096];
    __shared__ __align__(16) unsigned char a1buf[2][4096];
    __shared__ float a2buf[2][16 * 64];
    __shared__ float w3l[64];

    const int tid = threadIdx.x;
    const int wv = tid >> 6, l = tid & 63, l15 = l & 15, lg = l >> 4;
    const size_t row0 = (size_t)blockIdx.x * 16;
    const int ucol = wv * 16 + l15;

    short8 wf[3][4], uf[3][4];
#pragma unroll
    for (int g = 0; g < 3; ++g)
#pragma unroll
        for (int kt = 0; kt < 4; ++kt) {
            int n = g * 128 + ucol;
            int k0 = kt * 32 + lg * 8;
            wf[g][kt] = *(const short8*)(Wt + n * 128 + k0);
            uf[g][kt] = *(const short8*)(Ut + n * 128 + k0);
        }
    short8 waf[8];
#pragma unroll
    for (int kt = 0; kt < 8; ++kt)
        waf[kt] = *(const short8*)(WA + ucol * 256 + kt * 32 + lg * 8);
    short8 w2f[4];
    const int n2 = (wv & 3) * 16 + l15;
    if (wv < 4) {
#pragma unroll
        for (int kt = 0; kt < 4; ++kt)
            w2f[kt] = *(const short8*)(AW2 + n2 * 128 + kt * 32 + lg * 8);
    }
    const float b2v = (wv < 4) ? ab2[n2] : 0.f;
    const float b3v = b3[0];
    if (tid < 64) w3l[tid] = W3[tid];

    const float bx2 = gb[256 + ucol], bh2 = gb[640 + ucol];
    const float bz  = gb[ucol] + gb[384 + ucol];
    const float br  = gb[128 + ucol] + gb[512 + ucol];

    float nt4[4], news4[4];
    size_t hsbase[4];
#pragma unroll
    for (int j = 0; j < 4; ++j) {
        int m = lg * 4 + j;
        nt4[j]   = nterm[(row0 + m) * 128 + ucol];
        news4[j] = inputs[((row0 + m) * 51 + 50) * 128 + ucol];
        hsbase[j] = ((row0 + m) * 50) * 128 + ucol;
    }

    const int sr = tid >> 5, ss = tid & 31;
    const float* xsrc = inputs + (row0 + sr) * 51 * 128 + ss * 4;

    // hoisted LDS byte offsets
    int rdo[4], wro[4];
#pragma unroll
    for (int kt = 0; kt < 4; ++kt) rdo[kt] = swz(l15, kt * 64 + lg * 16, 256);
#pragma unroll
    for (int j = 0; j < 4; ++j)   wro[j] = swz(lg * 4 + j, ucol * 2, 256);
    const int xwo = swz(sr, ss * 8, 256);

    *(uint2*)(hbuf[0] + tid * 8) = make_uint2(0u, 0u);
    {
        float4 v = *(const float4*)(xsrc);
        *(uint2*)(xbuf[0] + xwo) = make_uint2(pk2(v.x, v.y), pk2(v.z, v.w));
    }
    float hreg[4] = {0.f, 0.f, 0.f, 0.f};
    __syncthreads();

#define STEP(T, PF, DOGRU, DOL1, DOL2, DODOT) do {                                  \
    const int p_ = (T) & 1;                                                          \
    float4 xpf_;                                                                     \
    if (PF) xpf_ = *(const float4*)(xsrc + (size_t)((T) + 1) * 128);                 \
    short8 ah_[4];                                                                   \
    if (DOGRU || DOL1) {                                                             \
        _Pragma("unroll")                                                            \
        for (int kt = 0; kt < 4; ++kt)                                               \
            ah_[kt] = *(const short8*)(hbuf[p_] + rdo[kt]);                          \
    }                                                                                \
    short8 ax_[4], pa_[4];                                                           \
    if (DOGRU) {                                                                     \
        _Pragma("unroll")                                                            \
        for (int kt = 0; kt < 4; ++kt)                                               \
            ax_[kt] = *(const short8*)(xbuf[p_] + rdo[kt]);                          \
    }                                                                                \
    if (DOL1) {                                                                      \
        _Pragma("unroll")                                                            \
        for (int kt = 0; kt < 4; ++kt)                                               \
            pa_[kt] = *(const short8*)(pbuf[p_] + rdo[kt]);                          \
    }                                                                                \
    f32x4 accx_[3], acch_[3], lacc_;                                                 \
    __builtin_amdgcn_s_setprio(1);                                                   \
    if (DOGRU) {                                                                     \
        _Pragma("unroll")                                                            \
        for (int g = 0; g < 3; ++g) {                                                \
            accx_[g] = (f32x4){0.f, 0.f, 0.f, 0.f};                                  \
            acch_[g] = (f32x4){0.f, 0.f, 0.f, 0.f};                                  \
        }                                                                            \
        _Pragma("unroll")                                                            \
        for (int kt = 0; kt < 4; ++kt)                                               \
            _Pragma("unroll")                                                        \
            for (int g = 0; g < 3; ++g) {                                            \
                accx_[g] = mfma16(ax_[kt], wf[g][kt], accx_[g]);                     \
                acch_[g] = mfma16(ah_[kt], uf[g][kt], acch_[g]);                     \
            }                                                                        \
    }                                                                                \
    if (DOL1) {                                                                      \
        lacc_ = (f32x4){0.f, 0.f, 0.f, 0.f};                                         \
        _Pragma("unroll")                                                            \
        for (int kt = 0; kt < 4; ++kt) lacc_ = mfma16(ah_[kt], waf[kt], lacc_);      \
        _Pragma("unroll")                                                            \
        for (int kt = 0; kt < 4; ++kt) lacc_ = mfma16(pa_[kt], waf[4 + kt], lacc_);  \
    }                                                                                \
    __builtin_amdgcn_s_setprio(0);                                                   \
    if (DOGRU) {                                                                     \
        _Pragma("unroll")                                                            \
        for (int j = 0; j < 4; ++j) {                                                \
            float z  = sigf(accx_[0][j] + acch_[0][j] + bz);                         \
            float r  = sigf(accx_[1][j] + acch_[1][j] + br);                         \
            float hc = tanhfast(accx_[2][j] + bx2 + r * (acch_[2][j] + bh2));        \
            float hn = fmaf(z, hreg[j] - hc, hc);                                    \
            hreg[j] = hn;                                                            \
            unsigned short hb = f2bf(hn);                                            \
            *(unsigned short*)(hbuf[p_ ^ 1] + wro[j]) = hb;                          \
            *(unsigned short*)(pbuf[p_ ^ 1] + wro[j]) = f2bf(hn * news4[j]);         \
            hs[hsbase[j] + (size_t)(T) * 128] = hb;                                  \
        }                                                                            \
    }                                                                                \
    if (DOL1) {                                                                      \
        _Pragma("unroll")                                                            \
        for (int j = 0; j < 4; ++j) {                                                \
            float v = fmaxf(lacc_[j] + nt4[j], 0.f);                                 \
            *(unsigned short*)(a1buf[p_] + wro[j]) = f2bf(v);                        \
        }                                                                            \
    }                                                                                \
    if (DOL2) {                                                                      \
        if (wv < 4) {                                                                \
            f32x4 c2_ = (f32x4){0.f, 0.f, 0.f, 0.f};                                 \
            _Pragma("unroll")                                                        \
            for (int kt = 0; kt < 4; ++kt) {                                         \
                short8 aa_ = *(const short8*)(a1buf[p_ ^ 1] + rdo[kt]);              \
                c2_ = mfma16(aa_, w2f[kt], c2_);                                     \
            }                                                                        \
            _Pragma("unroll")                                                        \
            for (int j = 0; j < 4; ++j)                                              \
                a2buf[p_][(lg * 4 + j) * 64 + n2] = fmaxf(c2_[j] + b2v, 0.f);        \
        }                                                                            \
    }                                                                                \
    if (DODOT) {                                                                     \
        if (tid < 256) {                                                             \
            int rrow_ = tid >> 5, cc_ = tid & 31;                                    \
            const float* a2r_ = &a2buf[p_ ^ 1][rrow_ * 64];                          \
            float s_ = a2r_[cc_] * w3l[cc_] + a2r_[cc_ + 32] * w3l[cc_ + 32];        \
            s_ += __shfl_xor(s_, 16, 32);                                            \
            s_ += __shfl_xor(s_, 8, 32);                                             \
            s_ += __shfl_xor(s_, 4, 32);                                             \
            s_ += __shfl_xor(s_, 2, 32);                                             \
            s_ += __shfl_xor(s_, 1, 32);                                             \
            if ((tid & 31) == 0)                                                     \
                ats[(row0 + rrow_) * 50 + ((T) - 3)] = sigf(s_ + b3v);               \
        }                                                                            \
    }                                                                                \
    if (PF)                                                                          \
        *(uint2*)(xbuf[p_ ^ 1] + xwo) =                                              \
            make_uint2(pk2(xpf_.x, xpf_.y), pk2(xpf_.z, xpf_.w));                    \
    __syncthreads();                                                                 \
} while (0)

    STEP(0, 1, 1, 0, 0, 0);
    STEP(1, 1, 1, 1, 0, 0);
    STEP(2, 1, 1, 1, 1, 0);
    for (int t = 3; t <= 48; ++t) STEP(t, 1, 1, 1, 1, 1);
    STEP(49, 0, 1, 1, 1, 1);
    STEP(50, 0, 0, 1, 1, 1);
    STEP(51, 0, 0, 0, 1, 1);
    STEP(52, 0, 0, 0, 0, 1);
#undef STEP
}

// ---------------- AUGRU: MFMA recurrence, single barrier per step ----------------
__global__ __launch_bounds__(512, 2) void augru_mfma(
    const unsigned short* __restrict__ hsrc, const unsigned short* __restrict__ Wt,
    const unsigned short* __restrict__ Ut, const float* __restrict__ bp,
    const float* __restrict__ ats, float* __restrict__ hf)
{
    __shared__ __align__(16) unsigned char xbuf[2][4096];
    __shared__ __align__(16) unsigned char hbuf[2][4096];
    __shared__ float atsl[16 * 50];

    const int tid = threadIdx.x;
    const int wv = tid >> 6, l = tid & 63, l15 = l & 15, lg = l >> 4;
    const size_t row0 = (size_t)blockIdx.x * 16;
    const int ucol = wv * 16 + l15;

    short8 wf[3][4], uf[3][4];
#pragma unroll
    for (int g = 0; g < 3; ++g)
#pragma unroll
        for (int kt = 0; kt < 4; ++kt) {
            int n = g * 128 + ucol;
            int k0 = kt * 32 + lg * 8;
            wf[g][kt] = *(const short8*)(Wt + n * 128 + k0);
            uf[g][kt] = *(const short8*)(Ut + n * 128 + k0);
        }
    const float bx0 = bp[ucol], bx1 = bp[128 + ucol], bx2 = bp[256 + ucol];

    const int sr = tid >> 5, ss = tid & 31;
    const unsigned short* xsrc = hsrc + (row0 + sr) * 50 * 128 + ss * 4;

    int rdo[4], wro[4];
#pragma unroll
    for (int kt = 0; kt < 4; ++kt) rdo[kt] = swz(l15, kt * 64 + lg * 16, 256);
#pragma unroll
    for (int j = 0; j < 4; ++j)   wro[j] = swz(lg * 4 + j, ucol * 2, 256);
    const int xwo = swz(sr, ss * 8, 256);

    *(uint2*)(hbuf[0] + tid * 8) = make_uint2(0u, 0u);
    if (tid < 400) {
        atsl[tid] = ats[row0 * 50 + tid];
        atsl[tid + 400] = ats[row0 * 50 + tid + 400];
    }
    {
        uint2 v = *(const uint2*)(xsrc);
        *(uint2*)(xbuf[0] + xwo) = v;
    }
    float hreg[4] = {0.f, 0.f, 0.f, 0.f};
    __syncthreads();

    for (int t = 0; t < 50; ++t) {
        const int p = t & 1;
        uint2 xnext;
        if (t < 49) xnext = *(const uint2*)(xsrc + (size_t)(t + 1) * 128);

        short8 ax[4], ah[4];
#pragma unroll
        for (int kt = 0; kt < 4; ++kt) {
            ax[kt] = *(const short8*)(xbuf[p] + rdo[kt]);
            ah[kt] = *(const short8*)(hbuf[p] + rdo[kt]);
        }
        f32x4 accx[3], acch[3];
#pragma unroll
        for (int g = 0; g < 3; ++g) {
            accx[g] = (f32x4){0.f, 0.f, 0.f, 0.f};
            acch[g] = (f32x4){0.f, 0.f, 0.f, 0.f};
        }
        __builtin_amdgcn_s_setprio(1);
#pragma unroll
        for (int kt = 0; kt < 4; ++kt)
#pragma unroll
            for (int g = 0; g < 3; ++g) {
                accx[g] = mfma16(ax[kt], wf[g][kt], accx[g]);
                acch[g] = mfma16(ah[kt], uf[g][kt], acch[g]);
            }
        __builtin_amdgcn_s_setprio(0);
#pragma unroll
        for (int j = 0; j < 4; ++j) {
            int m = lg * 4 + j;
            float u  = sigf(accx[0][j] + bx0 + acch[0][j]);
            float r  = sigf(accx[1][j] + bx1 + acch[1][j]);
            float c  = tanhfast(accx[2][j] + bx2 + r * acch[2][j]);
            float uu = atsl[m * 50 + t] * u;
            float hn = fmaf(uu, c - hreg[j], hreg[j]);
            hreg[j] = hn;
            *(unsigned short*)(hbuf[p ^ 1] + wro[j]) = f2bf(hn);
        }
        if (t < 49) *(uint2*)(xbuf[p ^ 1] + xwo) = xnext;
        __syncthreads();
    }
#pragma unroll
    for (int j = 0; j < 4; ++j)
        hf[(row0 + lg * 4 + j) * 128 + ucol] = hreg[j];
}

// ---------------- final: BN + 256->256->128->1, MFMA ----------------
__global__ __launch_bounds__(256, 2) void final_mfma(
    const float* __restrict__ hfv, const float* __restrict__ inputs,
    const float* __restrict__ gam, const float* __restrict__ bet,
    const float* __restrict__ mu, const float* __restrict__ var,
    const unsigned short* __restrict__ W1t, const float* __restrict__ b1,
    const unsigned short* __restrict__ W2t, const float* __restrict__ b2,
    const float* __restrict__ fW, const float* __restrict__ fb,
    float* __restrict__ out)
{
    __shared__ __align__(16) unsigned char xnb[16 * 512];
    __shared__ __align__(16) unsigned char d1b[16 * 512];
    __shared__ float d2b[16 * 132];
    __shared__ float wfl[128];

    const int tid = threadIdx.x;
    const int wv = tid >> 6, l = tid & 63, l15 = l & 15, lg = l >> 4;
    const size_t r0 = (size_t)blockIdx.x * 16;

    short8 w1f[4][8];
#pragma unroll
    for (int p = 0; p < 4; ++p)
#pragma unroll
        for (int kt = 0; kt < 8; ++kt) {
            int n = wv * 64 + p * 16 + l15;
            w1f[p][kt] = *(const short8*)(W1t + n * 256 + kt * 32 + lg * 8);
        }
    short8 w2f[2][8];
#pragma unroll
    for (int p = 0; p < 2; ++p)
#pragma unroll
        for (int kt = 0; kt < 8; ++kt) {
            int n = wv * 32 + p * 16 + l15;
            w2f[p][kt] = *(const short8*)(W2t + n * 256 + kt * 32 + lg * 8);
        }
    if (tid < 128) wfl[tid] = fW[tid];

    {
        int r = tid >> 4, c = tid & 15, k0 = c * 16;
        float v[16];
#pragma unroll
        for (int q = 0; q < 16; ++q) {
            int k = k0 + q;
            float x = (k < 128) ? hfv[(r0 + r) * 128 + k]
                                : inputs[((r0 + r) * 51 + 50) * 128 + (k - 128)];
            float s = gam[k] * rsqrtf(var[k] + 0.001f);
            v[q] = (x - mu[k]) * s + bet[k];
        }
        *(uint4*)(xnb + swz(r, k0 * 2, 512)) =
            make_uint4(pk2(v[0], v[1]), pk2(v[2], v[3]), pk2(v[4], v[5]), pk2(v[6], v[7]));
        *(uint4*)(xnb + swz(r, k0 * 2 + 16, 512)) =
            make_uint4(pk2(v[8], v[9]), pk2(v[10], v[11]), pk2(v[12], v[13]), pk2(v[14], v[15]));
    }
    __syncthreads();

    f32x4 a1[4];
#pragma unroll
    for (int p = 0; p < 4; ++p) a1[p] = (f32x4){0.f, 0.f, 0.f, 0.f};
#pragma unroll
    for (int kt = 0; kt < 8; ++kt) {
        short8 axx = *(const short8*)(xnb + swz(l15, kt * 64 + lg * 16, 512));
#pragma unroll
        for (int p = 0; p < 4; ++p) a1[p] = mfma16(axx, w1f[p][kt], a1[p]);
    }
#pragma unroll
    for (int p = 0; p < 4; ++p) {
        float bb = b1[wv * 64 + p * 16 + l15];
#pragma unroll
        for (int j = 0; j < 4; ++j) {
            int row = lg * 4 + j, col = wv * 64 + p * 16 + l15;
            *(unsigned short*)(d1b + swz(row, col * 2, 512)) = f2bf(lky(a1[p][j] + bb));
        }
    }
    __syncthreads();

    f32x4 a2[2];
#pragma unroll
    for (int p = 0; p < 2; ++p) a2[p] = (f32x4){0.f, 0.f, 0.f, 0.f};
#pragma unroll
    for (int kt = 0; kt < 8; ++kt) {
        short8 axx = *(const short8*)(d1b + swz(l15, kt * 64 + lg * 16, 512));
#pragma unroll
        for (int p = 0; p < 2; ++p) a2[p] = mfma16(axx, w2f[p][kt], a2[p]);
    }
#pragma unroll
    for (int p = 0; p < 2; ++p) {
        float bb = b2[wv * 32 + p * 16 + l15];
#pragma unroll
        for (int j = 0; j < 4; ++j)
            d2b[(lg * 4 + j) * 132 + wv * 32 + p * 16 + l15] = lky(a2[p][j] + bb);
    }
    __syncthreads();

    if (tid < 16) {
        float s = fb[0];
#pragma unroll 8
        for (int k = 0; k < 128; ++k) s += d2b[tid * 132 + k] * wfl[k];
        out[r0 + tid] = sigf(s);
    }
}

extern "C" void kernel_launch(void* const* d_in, const int* in_sizes, int n_in,
                              void* d_out, int out_size, void* d_ws, size_t ws_size,
                              hipStream_t stream)
{
    const float* inputs   = (const float*)d_in[0];
    const float* gru_W    = (const float*)d_in[1];
    const float* gru_U    = (const float*)d_in[2];
    const float* gru_b    = (const float*)d_in[3];
    const float* att_W1   = (const float*)d_in[4];
    const float* att_b1   = (const float*)d_in[5];
    const float* att_W2   = (const float*)d_in[6];
    const float* att_b2   = (const float*)d_in[7];
    const float* att_W3   = (const float*)d_in[8];
    const float* att_b3   = (const float*)d_in[9];
    const float* au_Wu    = (const float*)d_in[10];
    const float* au_bu    = (const float*)d_in[11];
    const float* au_Uu    = (const float*)d_in[12];
    const float* au_Wr    = (const float*)d_in[13];
    const float* au_br    = (const float*)d_in[14];
    const float* au_Ur    = (const float*)d_in[15];
    const float* au_Wc    = (const float*)d_in[16];
    const float* au_bc    = (const float*)d_in[17];
    const float* au_Uc    = (const float*)d_in[18];
    const float* bn_gamma = (const float*)d_in[19];
    const float* bn_beta  = (const float*)d_in[20];
    const float* bn_mean  = (const float*)d_in[21];
    const float* bn_var   = (const float*)d_in[22];
    const float* d_W1     = (const float*)d_in[23];
    const float* d_b1     = (const float*)d_in[24];
    const float* d_W2     = (const float*)d_in[25];
    const float* d_b2     = (const float*)d_in[26];
    const float* f_W      = (const float*)d_in[27];
    const float* f_b      = (const float*)d_in[28];

    char* w = (char*)d_ws;
    unsigned short* hs  = (unsigned short*)w;
    float* ats          = (float*)(w + 52428800);
    float* hf           = (float*)(w + 53248000);
    float* nterm        = (float*)(w + 55345152);
    unsigned short* Wg  = (unsigned short*)(w + 57442304);
    unsigned short* Ug  = (unsigned short*)(w + 57540608);
    unsigned short* Wau = (unsigned short*)(w + 57638912);
    unsigned short* Uau = (unsigned short*)(w + 57737216);
    unsigned short* WA  = (unsigned short*)(w + 57835520);
    unsigned short* WN  = (unsigned short*)(w + 57901056);
    unsigned short* AW2 = (unsigned short*)(w + 57933824);
    unsigned short* DW1 = (unsigned short*)(w + 57950208);
    unsigned short* DW2 = (unsigned short*)(w + 58081280);
    float* bp           = (float*)(w + 58146816);

    pack_all<<<994, 256, 0, stream>>>(
        gru_W, gru_U, au_Wu, au_Wr, au_Wc, au_Uu, au_Ur, au_Uc,
        att_W1, att_W2, d_W1, d_W2, au_bu, au_br, au_bc,
        Wg, Ug, Wau, Uau, WA, WN, AW2, DW1, DW2, bp);
    nterm_kernel<<<64, 512, 0, stream>>>(inputs, WN, att_b1, nterm);
    gru_attn<<<256, 512, 0, stream>>>(inputs, Wg, Ug, gru_b, WA, AW2, att_b2,
                                      nterm, att_W3, att_b3, hs, ats);
    augru_mfma<<<256, 512, 0, stream>>>(hs, Wau, Uau, bp, ats, hf);
    final_mfma<<<256, 256, 0, stream>>>(hf, inputs, bn_gamma, bn_beta, bn_mean, bn_var,
                                        DW1, d_b1, DW2, d_b2, f_W, f_b, (float*)d_out);
}